// Round 1
// baseline (778.142 us; speedup 1.0000x reference)
//
#include <hip/hip_runtime.h>

// RISnetPIv2: B=128, U=16, A=1024, FEAT=4, INFO=8.
// e_u/e_a are uniform averaging -> each 32-ch feature factors into
// ll[B,U,A,8] (bf16 ws), lg[B,U,8], gl[B,A,8], gg[B,8] (fp32).
// This version: 512-thread blocks = 4 u-chunks x 128 antennas (8 waves/SIMD
// vs 2 before: the old kernel was grid-starved at 18% occupancy), prep_base
// fused into layer_main (base computed into LDS), and the per-u lg reduction
// uses a channel-merging butterfly (10 shuffles vs 48) ending in one 8-lane
// atomicAdd. Workspace: 2x33.5MB bf16 ll + 16MB gl + <1MB misc.

#define NB 128
#define NU 16
#define NA 1024

static constexpr float PI_F = 3.14159265358979323846f;

__device__ __forceinline__ unsigned short f2bf(float f) {  // RNE
    unsigned int u = __float_as_uint(f);
    u += 0x7fffu + ((u >> 16) & 1u);
    return (unsigned short)(u >> 16);
}
__device__ __forceinline__ unsigned int pack2(float a, float b) {
    return (unsigned int)f2bf(a) | ((unsigned int)f2bf(b) << 16);
}
__device__ __forceinline__ void load8(const unsigned short* p, float x[8]) {
    uint4 v = *reinterpret_cast<const uint4*>(p);
    x[0] = __uint_as_float(v.x << 16); x[1] = __uint_as_float(v.x & 0xffff0000u);
    x[2] = __uint_as_float(v.y << 16); x[3] = __uint_as_float(v.y & 0xffff0000u);
    x[4] = __uint_as_float(v.z << 16); x[5] = __uint_as_float(v.z & 0xffff0000u);
    x[6] = __uint_as_float(v.w << 16); x[7] = __uint_as_float(v.w & 0xffff0000u);
}
__device__ __forceinline__ void store8(unsigned short* p, const float x[8]) {
    uint4 v;
    v.x = pack2(x[0], x[1]); v.y = pack2(x[2], x[3]);
    v.z = pack2(x[4], x[5]); v.w = pack2(x[6], x[7]);
    *reinterpret_cast<uint4*>(p) = v;
}

// Channel-merging butterfly over the 64-lane wave.
// Input: v[0..7] per lane. Output: full-wave sum of channel (lane&7),
// replicated across lanes. 10 shuffles total instead of 8x6=48.
__device__ __forceinline__ float chan_reduce8(const float* v, int lane) {
    float w[4];
    const bool s0 = (lane & 1) != 0;
#pragma unroll
    for (int k = 0; k < 4; ++k) {
        float lo = s0 ? v[2 * k + 1] : v[2 * k];
        float hi = s0 ? v[2 * k] : v[2 * k + 1];
        w[k] = lo + __shfl_xor(hi, 1, 64);
    }
    const bool s1 = (lane & 2) != 0;
#pragma unroll
    for (int k = 0; k < 2; ++k) {
        float lo = s1 ? w[2 * k + 1] : w[2 * k];
        float hi = s1 ? w[2 * k] : w[2 * k + 1];
        w[k] = lo + __shfl_xor(hi, 2, 64);
    }
    const bool s2 = (lane & 4) != 0;
    float lo = s2 ? w[1] : w[0];
    float hi = s2 ? w[0] : w[1];
    float r = lo + __shfl_xor(hi, 4, 64);
    r += __shfl_xor(r, 8, 64);
    r += __shfl_xor(r, 16, 64);
    r += __shfl_xor(r, 32, 64);
    return r;
}

// ---------------- Layer 1: input channel [B,4,U,A] ----------------
__global__ __launch_bounds__(512, 6) void layer_first(
    const float* __restrict__ ch, const float* __restrict__ W1,
    const float* __restrict__ b1, unsigned short* __restrict__ ll_out,
    float* __restrict__ lg_out, float* __restrict__ gl_out,
    float* __restrict__ gg_out)
{
    const int b = blockIdx.x;
    const int al = threadIdx.x & 127;
    const int uc = threadIdx.x >> 7;
    const int a = blockIdx.y * 128 + al;
    const int lane = threadIdx.x & 63;

    __shared__ float s_red[4][128][8];

    float glacc[8], ggacc[8];
#pragma unroll
    for (int i = 0; i < 8; ++i) { glacc[i] = 0.f; ggacc[i] = 0.f; }

#pragma unroll 1
    for (int k = 0; k < 4; ++k) {
        const int u = uc * 4 + k;
        float x[4];
#pragma unroll
        for (int c = 0; c < 4; ++c)
            x[c] = ch[(((size_t)b * 4 + c) * NU + u) * NA + a];

        float y[32];
#pragma unroll
        for (int o = 0; o < 32; ++o) y[o] = b1[o];
#pragma unroll
        for (int j = 0; j < 4; ++j)
#pragma unroll
            for (int c = 0; c < 4; ++c) {
                const float* wr = W1 + (j * 4 + c) * 8;
#pragma unroll
                for (int oi = 0; oi < 8; ++oi)
                    y[j * 8 + oi] = fmaf(x[c], wr[oi], y[j * 8 + oi]);
            }
#pragma unroll
        for (int o = 0; o < 32; ++o) y[o] = fmaxf(y[o], 0.f);

        const size_t xoff = (((size_t)(b * NU + u)) * NA + a) * 8;
        store8(ll_out + xoff, y);

#pragma unroll
        for (int i = 0; i < 8; ++i) glacc[i] += y[16 + i];
#pragma unroll
        for (int i = 0; i < 8; ++i) ggacc[i] += y[24 + i];

        float lr = chan_reduce8(y + 8, lane);
        if (lane < 8) atomicAdd(lg_out + (b * NU + u) * 8 + lane, lr);
    }

#pragma unroll
    for (int i = 0; i < 8; ++i) s_red[uc][al][i] = glacc[i];
    __syncthreads();
    if (uc == 0) {
        const float invU = 1.f / 16.f;
        float o8[8];
#pragma unroll
        for (int i = 0; i < 8; ++i)
            o8[i] = (s_red[0][al][i] + s_red[1][al][i] +
                     s_red[2][al][i] + s_red[3][al][i]) * invU;
        float4* gp = reinterpret_cast<float4*>(gl_out + ((size_t)b * NA + a) * 8);
        gp[0] = make_float4(o8[0], o8[1], o8[2], o8[3]);
        gp[1] = make_float4(o8[4], o8[5], o8[6], o8[7]);
    }
    float gr = chan_reduce8(ggacc, lane);
    if (lane < 8) atomicAdd(gg_out + b * 8 + lane, gr);
}

// ---------------- Layers 2..7 (prep_base fused) ----------------
// ll_in / ll_out may alias (per-thread read-then-write of same position).
__global__ __launch_bounds__(512, 6) void layer_main(
    const unsigned short* ll_in, const float* __restrict__ gl_in,
    const float* __restrict__ gl_skip,
    const float* __restrict__ lg_in, const float* __restrict__ lg_skip,
    const float* __restrict__ gg_in, const float* __restrict__ gg_skip,
    const float* __restrict__ Wl, const float* __restrict__ bl,
    const unsigned short* __restrict__ ll_skip,          // layer 7: f3 ll
    const float* __restrict__ ch, const float* __restrict__ W1,
    const float* __restrict__ b1,                        // layer 5: recompute f1 ll
    unsigned short* ll_out, float* __restrict__ lg_out,
    float* __restrict__ gl_out, float* __restrict__ gg_out)
{
    const int b = blockIdx.x;
    const int al = threadIdx.x & 127;
    const int uc = threadIdx.x >> 7;
    const int a = blockIdx.y * 128 + al;
    const int lane = threadIdx.x & 63;

    __shared__ float s_base[NU][32];      // 2 KB
    __shared__ float s_cgl[32][129];      // 16.5 KB, reused as s_red after u-loop

    // Phase A: base[u][o] = bias + lg·W_lg + gg·W_gg (one (u,o) per thread)
    {
        const int u = threadIdx.x >> 5, o = threadIdx.x & 31;
        const int j = o >> 3, oi = o & 7;
        const int t = b * NU + u;
        const float invA = 1.f / 1024.f, invUA = 1.f / 16384.f;
        float y = bl[o];
#pragma unroll
        for (int c = 0; c < 8; ++c) {
            float lg = lg_in[t * 8 + c] * invA;
            if (lg_skip) lg = (lg + lg_skip[t * 8 + c] * invA) * 0.5f;
            y = fmaf(lg, Wl[(j * 32 + 8 + c) * 8 + oi], y);
        }
#pragma unroll
        for (int c = 0; c < 8; ++c) {
            float gg = gg_in[b * 8 + c] * invUA;
            if (gg_skip) gg = (gg + gg_skip[b * 8 + c] * invUA) * 0.5f;
            y = fmaf(gg, Wl[(j * 32 + 24 + c) * 8 + oi], y);
        }
        s_base[u][o] = y;
    }

    // Phase B: this thread's j=uc slice of cgl (gl contribution), into LDS
    {
        float g[8];
        const float4* gp = reinterpret_cast<const float4*>(gl_in + ((size_t)b * NA + a) * 8);
        float4 g0 = gp[0], g1 = gp[1];
        if (gl_skip) {
            const float4* sp = reinterpret_cast<const float4*>(gl_skip + ((size_t)b * NA + a) * 8);
            float4 t0 = sp[0], t1 = sp[1];
            g0.x = (g0.x + t0.x) * 0.5f; g0.y = (g0.y + t0.y) * 0.5f;
            g0.z = (g0.z + t0.z) * 0.5f; g0.w = (g0.w + t0.w) * 0.5f;
            g1.x = (g1.x + t1.x) * 0.5f; g1.y = (g1.y + t1.y) * 0.5f;
            g1.z = (g1.z + t1.z) * 0.5f; g1.w = (g1.w + t1.w) * 0.5f;
        }
        g[0] = g0.x; g[1] = g0.y; g[2] = g0.z; g[3] = g0.w;
        g[4] = g1.x; g[5] = g1.y; g[6] = g1.z; g[7] = g1.w;

        float cj[8];
#pragma unroll
        for (int oi = 0; oi < 8; ++oi) cj[oi] = 0.f;
#pragma unroll
        for (int c = 0; c < 8; ++c) {
            const float* wr = Wl + (uc * 32 + 16 + c) * 8;
#pragma unroll
            for (int oi = 0; oi < 8; ++oi) cj[oi] = fmaf(g[c], wr[oi], cj[oi]);
        }
#pragma unroll
        for (int oi = 0; oi < 8; ++oi) s_cgl[uc * 8 + oi][al] = cj[oi];
    }
    __syncthreads();

    float cgl[32];
#pragma unroll
    for (int o = 0; o < 32; ++o) cgl[o] = s_cgl[o][al];
    __syncthreads();   // all cgl reads done before s_cgl is reused as s_red

    float glacc[8], ggacc[8];
#pragma unroll
    for (int i = 0; i < 8; ++i) { glacc[i] = 0.f; ggacc[i] = 0.f; }

#pragma unroll 1
    for (int k = 0; k < 4; ++k) {
        const int u = uc * 4 + k;
        float y[32];
#pragma unroll
        for (int o = 0; o < 32; ++o) y[o] = cgl[o] + s_base[u][o];

        const size_t xoff = (((size_t)(b * NU + u)) * NA + a) * 8;
        float x[8];
        load8(ll_in + xoff, x);
#pragma unroll
        for (int j = 0; j < 4; ++j)
#pragma unroll
            for (int c = 0; c < 8; ++c) {
                const float* wr = Wl + (j * 32 + c) * 8;  // wave-uniform
#pragma unroll
                for (int oi = 0; oi < 8; ++oi)
                    y[j * 8 + oi] = fmaf(x[c], wr[oi], y[j * 8 + oi]);
            }
#pragma unroll
        for (int o = 0; o < 32; ++o) y[o] = fmaxf(y[o], 0.f);

        float out8[8];
#pragma unroll
        for (int i = 0; i < 8; ++i) out8[i] = y[i];
        if (ll_skip) {                       // layer 7: average with stored f3 ll
            float s[8];
            load8(ll_skip + xoff, s);
#pragma unroll
            for (int i = 0; i < 8; ++i) out8[i] = (out8[i] + s[i]) * 0.5f;
        } else if (ch) {                     // layer 5: recompute f1 ll from input
            float xc[4];
#pragma unroll
            for (int c = 0; c < 4; ++c)
                xc[c] = ch[(((size_t)b * 4 + c) * NU + u) * NA + a];
            float s[8];
#pragma unroll
            for (int i = 0; i < 8; ++i) s[i] = b1[i];
#pragma unroll
            for (int c = 0; c < 4; ++c)
#pragma unroll
                for (int i = 0; i < 8; ++i)
                    s[i] = fmaf(xc[c], W1[c * 8 + i], s[i]);
#pragma unroll
            for (int i = 0; i < 8; ++i)
                out8[i] = (out8[i] + fmaxf(s[i], 0.f)) * 0.5f;
        }
        store8(ll_out + xoff, out8);

#pragma unroll
        for (int i = 0; i < 8; ++i) glacc[i] += y[16 + i];
#pragma unroll
        for (int i = 0; i < 8; ++i) ggacc[i] += y[24 + i];

        float lr = chan_reduce8(y + 8, lane);
        if (lane < 8) atomicAdd(lg_out + (b * NU + u) * 8 + lane, lr);
    }

    // gl cross-chunk reduce (reusing s_cgl storage)
    float (*s_red)[128][8] = reinterpret_cast<float (*)[128][8]>(&s_cgl[0][0]);
#pragma unroll
    for (int i = 0; i < 8; ++i) s_red[uc][al][i] = glacc[i];
    __syncthreads();
    if (uc == 0) {
        const float invU = 1.f / 16.f;
        float o8[8];
#pragma unroll
        for (int i = 0; i < 8; ++i)
            o8[i] = (s_red[0][al][i] + s_red[1][al][i] +
                     s_red[2][al][i] + s_red[3][al][i]) * invU;
        float4* gp = reinterpret_cast<float4*>(gl_out + ((size_t)b * NA + a) * 8);
        gp[0] = make_float4(o8[0], o8[1], o8[2], o8[3]);
        gp[1] = make_float4(o8[4], o8[5], o8[6], o8[7]);
    }
    float gr = chan_reduce8(ggacc, lane);
    if (lane < 8) atomicAdd(gg_out + b * 8 + lane, gr);
}

// ---------------- Layer 8: out[b,a] = pi * (mean_u f·W8 + b8) ----------------
__global__ __launch_bounds__(512, 6) void layer_out(
    const unsigned short* __restrict__ ll,   // f7' ll (skip already applied)
    const float* __restrict__ lg7, const float* __restrict__ lg3,  // raw sums
    const float* __restrict__ gl7, const float* __restrict__ gl3,  // means
    const float* __restrict__ gg7, const float* __restrict__ gg3,  // raw sums
    const float* __restrict__ W8, const float* __restrict__ b8,
    float* __restrict__ out)
{
    const int b = blockIdx.x;
    const int al = threadIdx.x & 127;
    const int uc = threadIdx.x >> 7;
    const int a = blockIdx.y * 128 + al;

    __shared__ float s_red[4][128];

    float acc = 0.f;
#pragma unroll 1
    for (int k = 0; k < 4; ++k) {
        const int u = uc * 4 + k;
        float x[8];
        load8(ll + (((size_t)(b * NU + u)) * NA + a) * 8, x);
#pragma unroll
        for (int c = 0; c < 8; ++c) acc += x[c] * W8[c];
    }
    s_red[uc][al] = acc;
    __syncthreads();
    if (uc != 0) return;

    const float invA = 1.f / 1024.f, invUA = 1.f / 16384.f, invU = 1.f / 16.f;
    acc = (s_red[0][al] + s_red[1][al] + s_red[2][al] + s_red[3][al]) * invU;

    float sb = b8[0];
#pragma unroll
    for (int c = 0; c < 8; ++c) {
        float s7 = 0.f, s3 = 0.f;
#pragma unroll
        for (int u = 0; u < NU; ++u) {
            s7 += lg7[(b * NU + u) * 8 + c];
            s3 += lg3[(b * NU + u) * 8 + c];
        }
        sb += ((s7 * invA + s3 * invA) * 0.5f * invU) * W8[8 + c];
    }
#pragma unroll
    for (int c = 0; c < 8; ++c)
        sb += ((gg7[b * 8 + c] + gg3[b * 8 + c]) * invUA * 0.5f) * W8[24 + c];

    {
        const float4* g7 = reinterpret_cast<const float4*>(gl7 + ((size_t)b * NA + a) * 8);
        const float4* g3 = reinterpret_cast<const float4*>(gl3 + ((size_t)b * NA + a) * 8);
        float4 a0 = g7[0], a1 = g7[1], b0 = g3[0], b1v = g3[1];
        acc += 0.5f * (a0.x + b0.x) * W8[16] + 0.5f * (a0.y + b0.y) * W8[17]
             + 0.5f * (a0.z + b0.z) * W8[18] + 0.5f * (a0.w + b0.w) * W8[19]
             + 0.5f * (a1.x + b1v.x) * W8[20] + 0.5f * (a1.y + b1v.y) * W8[21]
             + 0.5f * (a1.z + b1v.z) * W8[22] + 0.5f * (a1.w + b1v.w) * W8[23];
    }
    out[(size_t)b * NA + a] = (acc + sb) * PI_F;
}

extern "C" void kernel_launch(void* const* d_in, const int* in_sizes, int n_in,
                              void* d_out, int out_size, void* d_ws, size_t ws_size,
                              hipStream_t stream) {
    const float* channel = (const float*)d_in[0];
    const float* W1 = (const float*)d_in[1];
    const float* b1 = (const float*)d_in[2];
    const float* Wm = (const float*)d_in[3];
    const float* bm = (const float*)d_in[4];
    const float* W8 = (const float*)d_in[5];
    const float* b8 = (const float*)d_in[6];

    const size_t LL = (size_t)NB * NU * NA * 8;  // 16,777,216 elems
    const size_t GL = (size_t)NB * NA * 8;       // 1,048,576
    const size_t LG = (size_t)NB * NU * 8;       // 16,384
    const size_t GG = (size_t)NB * 8;            // 1,024

    unsigned short* cur = (unsigned short*)d_ws;        // bf16, 33.5 MB
    unsigned short* f3s = cur + LL;                     // bf16, 33.5 MB
    float* glb = (float*)(f3s + LL);                    // 4 x GL fp32, 16 MB
    float* g0 = glb, *g1 = glb + GL, *g2 = glb + 2 * GL, *g3 = glb + 3 * GL;
    float* lgb = glb + 4 * GL;                          // 7 x LG
    float* ggb = lgb + 7 * LG;                          // 7 x GG

    // zero atomic-sum buffers (lg + gg contiguous)
    hipMemsetAsync(lgb, 0, (7 * LG + 7 * GG) * sizeof(float), stream);

    dim3 grid(NB, NA / 128), blk(512);

    // L1: f1 -> cur, g0, lgb0, ggb0
    layer_first<<<grid, blk, 0, stream>>>(channel, W1, b1, cur, lgb, g0, ggb);

    // L2: cur -> cur (in-place), g0 -> g2
    layer_main<<<grid, blk, 0, stream>>>(cur, g0, nullptr,
        lgb, nullptr, ggb, nullptr, Wm, bm,
        nullptr, nullptr, nullptr, nullptr,
        cur, lgb + 1 * LG, g2, ggb + 1 * GG);

    // L3: cur -> f3s (pinned f3 copy), g2 -> g1
    layer_main<<<grid, blk, 0, stream>>>(cur, g2, nullptr,
        lgb + 1 * LG, nullptr, ggb + 1 * GG, nullptr, Wm + 1024, bm + 32,
        nullptr, nullptr, nullptr, nullptr,
        f3s, lgb + 2 * LG, g1, ggb + 2 * GG);

    // L4: f3s -> cur, g1 -> g3
    layer_main<<<grid, blk, 0, stream>>>(f3s, g1, nullptr,
        lgb + 2 * LG, nullptr, ggb + 2 * GG, nullptr, Wm + 2048, bm + 64,
        nullptr, nullptr, nullptr, nullptr,
        cur, lgb + 3 * LG, g3, ggb + 3 * GG);

    // L5: cur -> cur, g3 -> g2; ll-skip = recomputed f1 from channel
    layer_main<<<grid, blk, 0, stream>>>(cur, g3, nullptr,
        lgb + 3 * LG, nullptr, ggb + 3 * GG, nullptr, Wm + 3072, bm + 96,
        nullptr, channel, W1, b1,
        cur, lgb + 4 * LG, g2, ggb + 4 * GG);

    // L6: cur -> cur, g2 -> g3; input-side skip with f1 factors (lgb0/ggb0/g0)
    layer_main<<<grid, blk, 0, stream>>>(cur, g2, g0,
        lgb + 4 * LG, lgb, ggb + 4 * GG, ggb, Wm + 4096, bm + 128,
        nullptr, nullptr, nullptr, nullptr,
        cur, lgb + 5 * LG, g3, ggb + 5 * GG);

    // L7: cur -> cur, g3 -> g2; ll-skip = f3s
    layer_main<<<grid, blk, 0, stream>>>(cur, g3, nullptr,
        lgb + 5 * LG, nullptr, ggb + 5 * GG, nullptr, Wm + 5120, bm + 160,
        f3s, nullptr, nullptr, nullptr,
        cur, lgb + 6 * LG, g2, ggb + 6 * GG);

    // L8
    layer_out<<<grid, blk, 0, stream>>>(cur, lgb + 6 * LG, lgb + 2 * LG,
                                        g2, g1, ggb + 6 * GG, ggb + 2 * GG,
                                        W8, b8, (float*)d_out);
}

// Round 2
// 478.068 us; speedup vs baseline: 1.6277x; 1.6277x over previous
//
#include <hip/hip_runtime.h>

// RISnetPIv2: B=128, U=16, A=1024, FEAT=4, INFO=8.
// e_u/e_a uniform averaging -> 32-ch feature factors into ll[B,U,A,8] (bf16),
// lg[B,U,8], gl[B,A,8], gg[B,8] (fp32).
// Round-2: keep the proven 128-thread / 56-VGPR / zero-LDS layer body
// (round-1's 512-thr fused version spilled: VGPR forced to 40, FETCH 35->180MB).
// Occupancy is bought with grid.z u-split instead: NZ blocks each own NU/NZ
// users; gl becomes NZ partial buffers summed by consumers. 8 waves/SIMD at
// NZ=4 vs 2 before. lg/gg unchanged (atomics). 10-shuffle channel-merging
// lg reduction kept from round 1 (correctness-verified).

#define NB 128
#define NU 16
#define NA 1024

static constexpr float PI_F = 3.14159265358979323846f;

__device__ __forceinline__ unsigned short f2bf(float f) {  // RNE
    unsigned int u = __float_as_uint(f);
    u += 0x7fffu + ((u >> 16) & 1u);
    return (unsigned short)(u >> 16);
}
__device__ __forceinline__ unsigned int pack2(float a, float b) {
    return (unsigned int)f2bf(a) | ((unsigned int)f2bf(b) << 16);
}
__device__ __forceinline__ void load8(const unsigned short* p, float x[8]) {
    uint4 v = *reinterpret_cast<const uint4*>(p);
    x[0] = __uint_as_float(v.x << 16); x[1] = __uint_as_float(v.x & 0xffff0000u);
    x[2] = __uint_as_float(v.y << 16); x[3] = __uint_as_float(v.y & 0xffff0000u);
    x[4] = __uint_as_float(v.z << 16); x[5] = __uint_as_float(v.z & 0xffff0000u);
    x[6] = __uint_as_float(v.w << 16); x[7] = __uint_as_float(v.w & 0xffff0000u);
}
__device__ __forceinline__ void store8(unsigned short* p, const float x[8]) {
    uint4 v;
    v.x = pack2(x[0], x[1]); v.y = pack2(x[2], x[3]);
    v.z = pack2(x[4], x[5]); v.w = pack2(x[6], x[7]);
    *reinterpret_cast<uint4*>(p) = v;
}

// Channel-merging butterfly: input v[0..7] per lane; output = full-wave sum
// of channel (lane&7), replicated. 10 shuffles instead of 8x6=48.
__device__ __forceinline__ float chan_reduce8(const float* v, int lane) {
    float w[4];
    const bool s0 = (lane & 1) != 0;
#pragma unroll
    for (int k = 0; k < 4; ++k) {
        float lo = s0 ? v[2 * k + 1] : v[2 * k];
        float hi = s0 ? v[2 * k] : v[2 * k + 1];
        w[k] = lo + __shfl_xor(hi, 1, 64);
    }
    const bool s1 = (lane & 2) != 0;
#pragma unroll
    for (int k = 0; k < 2; ++k) {
        float lo = s1 ? w[2 * k + 1] : w[2 * k];
        float hi = s1 ? w[2 * k] : w[2 * k + 1];
        w[k] = lo + __shfl_xor(hi, 2, 64);
    }
    const bool s2 = (lane & 4) != 0;
    float lo = s2 ? w[1] : w[0];
    float hi = s2 ? w[0] : w[1];
    float r = lo + __shfl_xor(hi, 4, 64);
    r += __shfl_xor(r, 8, 64);
    r += __shfl_xor(r, 16, 64);
    r += __shfl_xor(r, 32, 64);
    return r;
}

// ---------------- Layer 1: input channel [B,4,U,A] ----------------
template <int NZ>
__global__ __launch_bounds__(128) void layer_first_t(
    const float* __restrict__ ch, const float* __restrict__ W1,
    const float* __restrict__ b1, unsigned short* __restrict__ ll_out,
    float* __restrict__ lg_out, float* __restrict__ gl_out,
    float* __restrict__ gg_out)
{
    constexpr int UN = NU / NZ;
    const int b = blockIdx.x;
    const int a = blockIdx.y * 128 + threadIdx.x;
    const int uz = blockIdx.z;
    const int lane = threadIdx.x & 63;

    float glacc[8], ggacc[8];
#pragma unroll
    for (int i = 0; i < 8; ++i) { glacc[i] = 0.f; ggacc[i] = 0.f; }

    for (int k = 0; k < UN; ++k) {
        const int u = uz * UN + k;
        float x[4];
#pragma unroll
        for (int c = 0; c < 4; ++c)
            x[c] = ch[(((size_t)b * 4 + c) * NU + u) * NA + a];

        float y[32];
#pragma unroll
        for (int o = 0; o < 32; ++o) y[o] = b1[o];
#pragma unroll
        for (int j = 0; j < 4; ++j)
#pragma unroll
            for (int c = 0; c < 4; ++c) {
                const float* wr = W1 + (j * 4 + c) * 8;
#pragma unroll
                for (int oi = 0; oi < 8; ++oi)
                    y[j * 8 + oi] = fmaf(x[c], wr[oi], y[j * 8 + oi]);
            }
#pragma unroll
        for (int o = 0; o < 32; ++o) y[o] = fmaxf(y[o], 0.f);

        const size_t xoff = (((size_t)(b * NU + u)) * NA + a) * 8;
        store8(ll_out + xoff, y);

#pragma unroll
        for (int i = 0; i < 8; ++i) glacc[i] += y[16 + i];
#pragma unroll
        for (int i = 0; i < 8; ++i) ggacc[i] += y[24 + i];

        float lr = chan_reduce8(y + 8, lane);
        if (lane < 8) atomicAdd(lg_out + (b * NU + u) * 8 + lane, lr);
    }
    {   // gl partial for this u-slice (already scaled by 1/U; partials sum to mean)
        const float invU = 1.f / 16.f;
        float4* gp = reinterpret_cast<float4*>(
            gl_out + (((size_t)uz * NB + b) * NA + a) * 8);
        gp[0] = make_float4(glacc[0]*invU, glacc[1]*invU, glacc[2]*invU, glacc[3]*invU);
        gp[1] = make_float4(glacc[4]*invU, glacc[5]*invU, glacc[6]*invU, glacc[7]*invU);
    }
    float gr = chan_reduce8(ggacc, lane);
    if (lane < 8) atomicAdd(gg_out + b * 8 + lane, gr);
}

// -------- prep: base[b,u,32] = bias + lg·W_lg + gg·W_gg (optional input skip) ----
__global__ __launch_bounds__(256) void prep_base_k(
    const float* __restrict__ lg_sum, const float* __restrict__ lg_skip,
    const float* __restrict__ gg_sum, const float* __restrict__ gg_skip,
    const float* __restrict__ Wl, const float* __restrict__ bl,
    float* __restrict__ base)
{
    const int t = blockIdx.x * 256 + threadIdx.x;  // b*16+u
    if (t >= NB * NU) return;
    const int b = t >> 4;
    const float invA = 1.f / 1024.f, invUA = 1.f / 16384.f;
    float lg[8], gg[8];
#pragma unroll
    for (int c = 0; c < 8; ++c) {
        float v = lg_sum[t * 8 + c] * invA;
        if (lg_skip) v = (v + lg_skip[t * 8 + c] * invA) * 0.5f;
        lg[c] = v;
    }
#pragma unroll
    for (int c = 0; c < 8; ++c) {
        float v = gg_sum[b * 8 + c] * invUA;
        if (gg_skip) v = (v + gg_skip[b * 8 + c] * invUA) * 0.5f;
        gg[c] = v;
    }
    float y[32];
#pragma unroll
    for (int o = 0; o < 32; ++o) y[o] = bl[o];
#pragma unroll
    for (int j = 0; j < 4; ++j)
#pragma unroll
        for (int c = 0; c < 8; ++c) {
            const float* wl = Wl + (j * 32 + 8 + c) * 8;
            const float* wg = Wl + (j * 32 + 24 + c) * 8;
#pragma unroll
            for (int oi = 0; oi < 8; ++oi) {
                y[j * 8 + oi] = fmaf(lg[c], wl[oi], y[j * 8 + oi]);
                y[j * 8 + oi] = fmaf(gg[c], wg[oi], y[j * 8 + oi]);
            }
        }
#pragma unroll
    for (int o = 0; o < 32; ++o) base[t * 32 + o] = y[o];
}

// ---------------- Layers 2..7 main ----------------
// ll_in / ll_out may alias (per-thread read-then-write of same position;
// z-blocks own disjoint u-slices).
template <int NZ>
__global__ __launch_bounds__(128) void layer_main_t(
    const unsigned short* ll_in, const float* __restrict__ gl_in,
    const float* __restrict__ gl_skip, const float* __restrict__ base,
    const float* __restrict__ Wl,
    const unsigned short* __restrict__ ll_skip,          // layer 7: f3 ll
    const float* __restrict__ ch, const float* __restrict__ W1,
    const float* __restrict__ b1,                        // layer 5: recompute f1 ll
    unsigned short* ll_out, float* __restrict__ lg_out,
    float* __restrict__ gl_out, float* __restrict__ gg_out)
{
    constexpr int UN = NU / NZ;
    const int b = blockIdx.x;
    const int a = blockIdx.y * 128 + threadIdx.x;
    const int uz = blockIdx.z;
    const int lane = threadIdx.x & 63;

    float g[8];
    {
        float si[8];
#pragma unroll
        for (int i = 0; i < 8; ++i) si[i] = 0.f;
#pragma unroll
        for (int z = 0; z < NZ; ++z) {
            const float4* gp = reinterpret_cast<const float4*>(
                gl_in + (((size_t)z * NB + b) * NA + a) * 8);
            float4 g0 = gp[0], g1 = gp[1];
            si[0] += g0.x; si[1] += g0.y; si[2] += g0.z; si[3] += g0.w;
            si[4] += g1.x; si[5] += g1.y; si[6] += g1.z; si[7] += g1.w;
        }
        if (gl_skip) {
            float ss[8];
#pragma unroll
            for (int i = 0; i < 8; ++i) ss[i] = 0.f;
#pragma unroll
            for (int z = 0; z < NZ; ++z) {
                const float4* sp = reinterpret_cast<const float4*>(
                    gl_skip + (((size_t)z * NB + b) * NA + a) * 8);
                float4 s0 = sp[0], s1 = sp[1];
                ss[0] += s0.x; ss[1] += s0.y; ss[2] += s0.z; ss[3] += s0.w;
                ss[4] += s1.x; ss[5] += s1.y; ss[6] += s1.z; ss[7] += s1.w;
            }
#pragma unroll
            for (int i = 0; i < 8; ++i) g[i] = (si[i] + ss[i]) * 0.5f;
        } else {
#pragma unroll
            for (int i = 0; i < 8; ++i) g[i] = si[i];
        }
    }
    float cgl[32];
#pragma unroll
    for (int o = 0; o < 32; ++o) cgl[o] = 0.f;
#pragma unroll
    for (int j = 0; j < 4; ++j)
#pragma unroll
        for (int c = 0; c < 8; ++c) {
            const float* wr = Wl + (j * 32 + 16 + c) * 8;
#pragma unroll
            for (int oi = 0; oi < 8; ++oi)
                cgl[j * 8 + oi] = fmaf(g[c], wr[oi], cgl[j * 8 + oi]);
        }

    float glacc[8], ggacc[8];
#pragma unroll
    for (int i = 0; i < 8; ++i) { glacc[i] = 0.f; ggacc[i] = 0.f; }

    for (int k = 0; k < UN; ++k) {
        const int u = uz * UN + k;
        const float* bp = base + (b * NU + u) * 32;  // wave-uniform -> s_load
        float y[32];
#pragma unroll
        for (int o = 0; o < 32; ++o) y[o] = cgl[o] + bp[o];

        const size_t xoff = (((size_t)(b * NU + u)) * NA + a) * 8;
        float x[8];
        load8(ll_in + xoff, x);
#pragma unroll
        for (int j = 0; j < 4; ++j)
#pragma unroll
            for (int c = 0; c < 8; ++c) {
                const float* wr = Wl + (j * 32 + c) * 8;  // wave-uniform
#pragma unroll
                for (int oi = 0; oi < 8; ++oi)
                    y[j * 8 + oi] = fmaf(x[c], wr[oi], y[j * 8 + oi]);
            }
#pragma unroll
        for (int o = 0; o < 32; ++o) y[o] = fmaxf(y[o], 0.f);

        float out8[8];
#pragma unroll
        for (int i = 0; i < 8; ++i) out8[i] = y[i];
        if (ll_skip) {                       // layer 7: average with stored f3 ll
            float s[8];
            load8(ll_skip + xoff, s);
#pragma unroll
            for (int i = 0; i < 8; ++i) out8[i] = (out8[i] + s[i]) * 0.5f;
        } else if (ch) {                     // layer 5: recompute f1 ll from input
            float xc[4];
#pragma unroll
            for (int c = 0; c < 4; ++c)
                xc[c] = ch[(((size_t)b * 4 + c) * NU + u) * NA + a];
            float s[8];
#pragma unroll
            for (int i = 0; i < 8; ++i) s[i] = b1[i];
#pragma unroll
            for (int c = 0; c < 4; ++c)
#pragma unroll
                for (int i = 0; i < 8; ++i)
                    s[i] = fmaf(xc[c], W1[c * 8 + i], s[i]);
#pragma unroll
            for (int i = 0; i < 8; ++i)
                out8[i] = (out8[i] + fmaxf(s[i], 0.f)) * 0.5f;
        }
        store8(ll_out + xoff, out8);

#pragma unroll
        for (int i = 0; i < 8; ++i) glacc[i] += y[16 + i];
#pragma unroll
        for (int i = 0; i < 8; ++i) ggacc[i] += y[24 + i];

        float lr = chan_reduce8(y + 8, lane);
        if (lane < 8) atomicAdd(lg_out + (b * NU + u) * 8 + lane, lr);
    }
    {
        const float invU = 1.f / 16.f;
        float4* gp = reinterpret_cast<float4*>(
            gl_out + (((size_t)uz * NB + b) * NA + a) * 8);
        gp[0] = make_float4(glacc[0]*invU, glacc[1]*invU, glacc[2]*invU, glacc[3]*invU);
        gp[1] = make_float4(glacc[4]*invU, glacc[5]*invU, glacc[6]*invU, glacc[7]*invU);
    }
    float gr = chan_reduce8(ggacc, lane);
    if (lane < 8) atomicAdd(gg_out + b * 8 + lane, gr);
}

// ---------------- Layer 8: out[b,a] = pi * (mean_u f·W8 + b8) ----------------
// z-split partials accumulate via atomicAdd into a zeroed output.
template <int NZ>
__global__ __launch_bounds__(128) void layer_out_t(
    const unsigned short* __restrict__ ll,   // f7' ll (skip already applied)
    const float* __restrict__ lg7, const float* __restrict__ lg3,  // raw sums
    const float* __restrict__ gl7, const float* __restrict__ gl3,  // partial means
    const float* __restrict__ gg7, const float* __restrict__ gg3,  // raw sums
    const float* __restrict__ W8, const float* __restrict__ b8,
    float* __restrict__ out)
{
    constexpr int UN = NU / NZ;
    const int b = blockIdx.x;
    const int a = blockIdx.y * 128 + threadIdx.x;
    const int uz = blockIdx.z;
    const float invA = 1.f / 1024.f, invUA = 1.f / 16384.f, invU = 1.f / 16.f;

    float acc = 0.f;
    for (int k = 0; k < UN; ++k) {
        const int u = uz * UN + k;
        float x[8];
        load8(ll + (((size_t)(b * NU + u)) * NA + a) * 8, x);
#pragma unroll
        for (int c = 0; c < 8; ++c) acc += x[c] * W8[c];
    }
    acc *= invU;

    if (uz == 0) {
        float sb = b8[0];
#pragma unroll
        for (int c = 0; c < 8; ++c) {
            float s7 = 0.f, s3 = 0.f;
#pragma unroll
            for (int u = 0; u < NU; ++u) {
                s7 += lg7[(b * NU + u) * 8 + c];
                s3 += lg3[(b * NU + u) * 8 + c];
            }
            sb += ((s7 * invA + s3 * invA) * 0.5f * invU) * W8[8 + c];
        }
#pragma unroll
        for (int c = 0; c < 8; ++c)
            sb += ((gg7[b * 8 + c] + gg3[b * 8 + c]) * invUA * 0.5f) * W8[24 + c];

        float s7[8], s3[8];
#pragma unroll
        for (int i = 0; i < 8; ++i) { s7[i] = 0.f; s3[i] = 0.f; }
#pragma unroll
        for (int z = 0; z < NZ; ++z) {
            const float4* g7 = reinterpret_cast<const float4*>(
                gl7 + (((size_t)z * NB + b) * NA + a) * 8);
            const float4* g3 = reinterpret_cast<const float4*>(
                gl3 + (((size_t)z * NB + b) * NA + a) * 8);
            float4 a0 = g7[0], a1 = g7[1], b0 = g3[0], b1v = g3[1];
            s7[0] += a0.x; s7[1] += a0.y; s7[2] += a0.z; s7[3] += a0.w;
            s7[4] += a1.x; s7[5] += a1.y; s7[6] += a1.z; s7[7] += a1.w;
            s3[0] += b0.x; s3[1] += b0.y; s3[2] += b0.z; s3[3] += b0.w;
            s3[4] += b1v.x; s3[5] += b1v.y; s3[6] += b1v.z; s3[7] += b1v.w;
        }
#pragma unroll
        for (int i = 0; i < 8; ++i)
            acc += 0.5f * (s7[i] + s3[i]) * W8[16 + i];
        acc += sb;
    }
    atomicAdd(out + (size_t)b * NA + a, acc * PI_F);
}

// ---------------- host ----------------
static constexpr size_t LLsz = (size_t)NB * NU * NA * 8;  // elems
static constexpr size_t GLsz = (size_t)NB * NA * 8;
static constexpr size_t LGsz = (size_t)NB * NU * 8;
static constexpr size_t GGsz = (size_t)NB * 8;

template <int NZ>
static void run_pipeline(const float* channel, const float* W1, const float* b1,
                         const float* Wm, const float* bm, const float* W8,
                         const float* b8, float* out, int out_bytes,
                         void* d_ws, hipStream_t stream)
{
    unsigned short* cur = (unsigned short*)d_ws;        // bf16 ll
    unsigned short* f3s = cur + LLsz;                   // bf16 f3 ll copy
    float* glb = (float*)(f3s + LLsz);                  // 4 bufs x NZ*GL fp32
    float* g0 = glb;
    float* g1 = glb + (size_t)NZ * GLsz;
    float* g2 = glb + (size_t)2 * NZ * GLsz;
    float* g3 = glb + (size_t)3 * NZ * GLsz;
    float* lgb = glb + (size_t)4 * NZ * GLsz;           // 7 x LG
    float* ggb = lgb + 7 * LGsz;                        // 7 x GG
    float* base = ggb + 7 * GGsz;                       // 2048 x 32

    hipMemsetAsync(lgb, 0, (7 * LGsz + 7 * GGsz) * sizeof(float), stream);
    hipMemsetAsync(out, 0, out_bytes, stream);

    dim3 grid(NB, NA / 128, NZ), blk(128);

    // L1: f1 -> cur, g0, lgb0, ggb0
    layer_first_t<NZ><<<grid, blk, 0, stream>>>(channel, W1, b1, cur, lgb, g0, ggb);

    // L2: cur -> cur (in-place), g0 -> g2
    prep_base_k<<<8, 256, 0, stream>>>(lgb, nullptr, ggb, nullptr, Wm, bm, base);
    layer_main_t<NZ><<<grid, blk, 0, stream>>>(cur, g0, nullptr, base, Wm,
        nullptr, nullptr, nullptr, nullptr,
        cur, lgb + 1 * LGsz, g2, ggb + 1 * GGsz);

    // L3: cur -> f3s (pinned f3 copy), g2 -> g1
    prep_base_k<<<8, 256, 0, stream>>>(lgb + 1 * LGsz, nullptr, ggb + 1 * GGsz, nullptr,
                                       Wm + 1024, bm + 32, base);
    layer_main_t<NZ><<<grid, blk, 0, stream>>>(cur, g2, nullptr, base, Wm + 1024,
        nullptr, nullptr, nullptr, nullptr,
        f3s, lgb + 2 * LGsz, g1, ggb + 2 * GGsz);

    // L4: f3s -> cur, g1 -> g3
    prep_base_k<<<8, 256, 0, stream>>>(lgb + 2 * LGsz, nullptr, ggb + 2 * GGsz, nullptr,
                                       Wm + 2048, bm + 64, base);
    layer_main_t<NZ><<<grid, blk, 0, stream>>>(f3s, g1, nullptr, base, Wm + 2048,
        nullptr, nullptr, nullptr, nullptr,
        cur, lgb + 3 * LGsz, g3, ggb + 3 * GGsz);

    // L5: cur -> cur, g3 -> g2; ll-skip = recomputed f1 from channel
    prep_base_k<<<8, 256, 0, stream>>>(lgb + 3 * LGsz, nullptr, ggb + 3 * GGsz, nullptr,
                                       Wm + 3072, bm + 96, base);
    layer_main_t<NZ><<<grid, blk, 0, stream>>>(cur, g3, nullptr, base, Wm + 3072,
        nullptr, channel, W1, b1,
        cur, lgb + 4 * LGsz, g2, ggb + 4 * GGsz);

    // L6: cur -> cur, g2 -> g3; input-side skip with f1 factors (lgb0/ggb0/g0)
    prep_base_k<<<8, 256, 0, stream>>>(lgb + 4 * LGsz, lgb, ggb + 4 * GGsz, ggb,
                                       Wm + 4096, bm + 128, base);
    layer_main_t<NZ><<<grid, blk, 0, stream>>>(cur, g2, g0, base, Wm + 4096,
        nullptr, nullptr, nullptr, nullptr,
        cur, lgb + 5 * LGsz, g3, ggb + 5 * GGsz);

    // L7: cur -> cur, g3 -> g2; ll-skip = f3s
    prep_base_k<<<8, 256, 0, stream>>>(lgb + 5 * LGsz, nullptr, ggb + 5 * GGsz, nullptr,
                                       Wm + 5120, bm + 160, base);
    layer_main_t<NZ><<<grid, blk, 0, stream>>>(cur, g3, nullptr, base, Wm + 5120,
        f3s, nullptr, nullptr, nullptr,
        cur, lgb + 6 * LGsz, g2, ggb + 6 * GGsz);

    // L8
    layer_out_t<NZ><<<grid, blk, 0, stream>>>(cur, lgb + 6 * LGsz, lgb + 2 * LGsz,
                                              g2, g1, ggb + 6 * GGsz, ggb + 2 * GGsz,
                                              W8, b8, out);
}

static size_t ws_req(int nz) {
    return LLsz * 2 * sizeof(unsigned short) * 2 / 2    // cur + f3s (bf16)
         + (size_t)4 * nz * GLsz * sizeof(float)
         + (7 * LGsz + 7 * GGsz + 2048 * 32) * sizeof(float);
}

extern "C" void kernel_launch(void* const* d_in, const int* in_sizes, int n_in,
                              void* d_out, int out_size, void* d_ws, size_t ws_size,
                              hipStream_t stream) {
    const float* channel = (const float*)d_in[0];
    const float* W1 = (const float*)d_in[1];
    const float* b1 = (const float*)d_in[2];
    const float* Wm = (const float*)d_in[3];
    const float* bm = (const float*)d_in[4];
    const float* W8 = (const float*)d_in[5];
    const float* b8 = (const float*)d_in[6];
    float* out = (float*)d_out;

    if (ws_size >= ws_req(4)) {
        run_pipeline<4>(channel, W1, b1, Wm, bm, W8, b8, out, out_size, d_ws, stream);
    } else if (ws_size >= ws_req(2)) {
        run_pipeline<2>(channel, W1, b1, Wm, bm, W8, b8, out, out_size, d_ws, stream);
    } else {
        run_pipeline<1>(channel, W1, b1, Wm, bm, W8, b8, out, out_size, d_ws, stream);
    }
}